// Round 1
// baseline (584.706 us; speedup 1.0000x reference)
//
#include <hip/hip_runtime.h>

#define NCH 32

// Factorized 1D sparse conv: out[p][d] = sum_{k,c} f[idx[k][p]][c] * W[k][c][d],
// idx==n means missing neighbor -> zero contribution (skip).
// One thread per point, 32 fp32 accumulators. W reads are wave-uniform -> SGPR.
__global__ __launch_bounds__(256) void conv1d_kernel(
    const float* __restrict__ f, const float* __restrict__ W,
    const int* __restrict__ idx, float* __restrict__ out, int n)
{
    int p = blockIdx.x * 256 + threadIdx.x;
    if (p >= n) return;

    float acc[NCH];
#pragma unroll
    for (int ch = 0; ch < NCH; ++ch) acc[ch] = 0.f;

#pragma unroll
    for (int k = 0; k < 3; ++k) {
        int i = idx[(size_t)k * n + p];
        if (i >= n) continue;                       // missing neighbor -> zeros
        const float4* row = (const float4*)(f + (size_t)i * NCH);
        const float* wk = W + k * NCH * NCH;
#pragma unroll
        for (int c4 = 0; c4 < NCH / 4; ++c4) {
            float4 g4 = row[c4];
            const float* w = wk + (size_t)c4 * 4 * NCH;
#pragma unroll
            for (int ch = 0; ch < NCH; ++ch) acc[ch] = fmaf(g4.x, w[ch], acc[ch]);
            w += NCH;
#pragma unroll
            for (int ch = 0; ch < NCH; ++ch) acc[ch] = fmaf(g4.y, w[ch], acc[ch]);
            w += NCH;
#pragma unroll
            for (int ch = 0; ch < NCH; ++ch) acc[ch] = fmaf(g4.z, w[ch], acc[ch]);
            w += NCH;
#pragma unroll
            for (int ch = 0; ch < NCH; ++ch) acc[ch] = fmaf(g4.w, w[ch], acc[ch]);
        }
    }

    float4* orow = (float4*)(out + (size_t)p * NCH);
#pragma unroll
    for (int c4 = 0; c4 < NCH / 4; ++c4) {
        float4 v;
        v.x = acc[c4 * 4 + 0];
        v.y = acc[c4 * 4 + 1];
        v.z = acc[c4 * 4 + 2];
        v.w = acc[c4 * 4 + 3];
        orow[c4] = v;
    }
}

// Per-channel sum and sum-of-squares over all n rows of h [n,32].
// stats[0..31] = sum, stats[32..63] = sumsq. Must be zeroed beforehand.
__global__ __launch_bounds__(256) void stats_kernel(
    const float* __restrict__ h, float* __restrict__ stats, int n)
{
    __shared__ float lsum[4][NCH];
    __shared__ float lsq[4][NCH];

    long total = (long)n * NCH;
    long tid = (long)blockIdx.x * 256 + threadIdx.x;
    long stride = (long)gridDim.x * 256;   // multiple of 32 -> channel fixed per thread
    int ch = threadIdx.x & 31;

    float s = 0.f, q = 0.f;
    for (long i = tid; i < total; i += stride) {
        float v = h[i];
        s += v;
        q = fmaf(v, v, q);
    }
    // merge lane and lane^32 (same channel within the wave64)
    s += __shfl_xor(s, 32);
    q += __shfl_xor(q, 32);

    int wave = threadIdx.x >> 6;
    if ((threadIdx.x & 63) < 32) {
        lsum[wave][ch] = s;
        lsq[wave][ch] = q;
    }
    __syncthreads();
    if (threadIdx.x < 32) {
        float S = lsum[0][ch] + lsum[1][ch] + lsum[2][ch] + lsum[3][ch];
        float Q = lsq[0][ch] + lsq[1][ch] + lsq[2][ch] + lsq[3][ch];
        atomicAdd(&stats[ch], S);
        atomicAdd(&stats[NCH + ch], Q);
    }
}

// BatchNorm (batch stats) + ReLU, in place on h [n,32]. One float4 per thread.
__global__ __launch_bounds__(256) void bn_relu_kernel(
    float* h, const float* __restrict__ stats,
    const float* __restrict__ gamma, const float* __restrict__ beta, int n)
{
    long tid = (long)blockIdx.x * 256 + threadIdx.x;
    long total4 = (long)n * NCH / 4;
    if (tid >= total4) return;

    int ch0 = ((int)(tid & 7)) * 4;
    float inv_n = 1.f / (float)n;

    float4 v = ((const float4*)h)[tid];
    float r[4] = {v.x, v.y, v.z, v.w};
#pragma unroll
    for (int j = 0; j < 4; ++j) {
        int ch = ch0 + j;
        float mean = stats[ch] * inv_n;
        float var = stats[NCH + ch] * inv_n - mean * mean;
        float scale = gamma[ch] * rsqrtf(var + 1e-5f);
        float shift = beta[ch] - mean * scale;
        float o = fmaf(r[j], scale, shift);
        r[j] = o > 0.f ? o : 0.f;
    }
    float4 o4;
    o4.x = r[0]; o4.y = r[1]; o4.z = r[2]; o4.w = r[3];
    ((float4*)h)[tid] = o4;
}

extern "C" void kernel_launch(void* const* d_in, const int* in_sizes, int n_in,
                              void* d_out, int out_size, void* d_ws, size_t ws_size,
                              hipStream_t stream)
{
    const float* feats = (const float*)d_in[0];
    const float* W1    = (const float*)d_in[1];
    const float* W2    = (const float*)d_in[2];
    const float* W3    = (const float*)d_in[3];
    const float* gamma = (const float*)d_in[4];
    const float* beta  = (const float*)d_in[5];
    const int*   nbr   = (const int*)d_in[6];   // [3 axes][3 taps][n]

    int n = in_sizes[0] / NCH;

    float* hout = (float*)d_out;                 // h1, then h3, then final out
    float* h2   = (float*)d_ws;                  // n*32 floats
    float* stats = h2 + (size_t)n * NCH;         // 64 floats

    int cblocks = (n + 255) / 256;

    // conv1: axis 2 (z), feats -> d_out
    conv1d_kernel<<<cblocks, 256, 0, stream>>>(feats, W1, nbr + (size_t)2 * 3 * n, hout, n);
    // conv2: axis 1 (y), d_out -> ws
    conv1d_kernel<<<cblocks, 256, 0, stream>>>(hout, W2, nbr + (size_t)1 * 3 * n, h2, n);
    // conv3: axis 0 (x), ws -> d_out
    conv1d_kernel<<<cblocks, 256, 0, stream>>>(h2, W3, nbr + (size_t)0 * 3 * n, hout, n);

    // BN stats (zero the accumulators first; ws is poisoned each call)
    hipMemsetAsync(stats, 0, 2 * NCH * sizeof(float), stream);
    stats_kernel<<<512, 256, 0, stream>>>(hout, stats, n);

    // BN + ReLU in place
    long total4 = (long)n * NCH / 4;
    int nblocks = (int)((total4 + 255) / 256);
    bn_relu_kernel<<<nblocks, 256, 0, stream>>>(hout, stats, gamma, beta, n);
}